// Round 11
// baseline (261.112 us; speedup 1.0000x reference)
//
#include <hip/hip_runtime.h>
#include <math.h>

#define NU 3
#define BB 16
#define NN 1024
#define DD 256
#define MM (BB*NN)      // 16384 tokens per util
#define NPAIR 6

// workspace layout (float element offsets)
#define OFF_UNARY  0
#define OFF_INVXS  (OFF_UNARY + NU*MM)
#define OFF_INVXP  (OFF_INVXS + NU*MM)
#define OFF_INVYP  (OFF_INVXP + NPAIR*MM)
#define OFF_YBAR   (OFF_INVYP + NPAIR*MM)          // bars contiguous for one memset
#define OFF_XPBAR  (OFF_YBAR + NU*BB*DD)
#define OFF_YPBAR  (OFF_XPBAR + NPAIR*BB*DD)
#define OFF_PROJS  (OFF_YPBAR + NPAIR*BB*DD)
#define OFF_PROJX  (OFF_PROJS + NU*BB*DD)
#define OFF_PROJY  (OFF_PROJX + NPAIR*BB*DD)
#define OFF_CSS    (OFF_PROJY + NPAIR*BB*DD)
#define OFF_CSX    (OFF_CSS + NU*BB)
#define OFF_CSY    (OFF_CSX + NPAIR*BB)
#define OFF_SELFP  (OFF_CSY + NPAIR*BB)
#define OFF_POTX   (OFF_SELFP + NU*MM)
#define OFF_POTY   (OFF_POTX + NPAIR*MM)
#define WS_FLOATS  (OFF_POTY + NPAIR*MM)           // = 663792
// f16 weights, fragment order: 21 slots x 65536 halves = 688128 floats
#define OFF_PROB   (WS_FLOATS + 21*32768)
#define OFF_PART   (OFF_PROB + 9*BB*NN)
// end = OFF_PART + 9*BB*8*DD  (~7.2 MB total)

typedef _Float16 half8 __attribute__((ext_vector_type(8)));
typedef float f32x4 __attribute__((ext_vector_type(4)));

__device__ __forceinline__ const float* selU(int u, const float* u0, const float* u1, const float* u2) {
    return u == 0 ? u0 : (u == 1 ? u1 : u2);
}
__device__ __forceinline__ half8 cvt8(float4 a, float4 b) {
    half8 h = { (_Float16)a.x,(_Float16)a.y,(_Float16)a.z,(_Float16)a.w,
                (_Float16)b.x,(_Float16)b.y,(_Float16)b.z,(_Float16)b.w };
    return h;
}

// ---------------------------------------------------------------------------
// Weight convert: fp32 -> f16, fragment order. Slot (u, s=0..6):
// s0 Wu[u]; s1 Wsx[u]; s2 Wsy[u]; s3/s4 Wpx[u->j0/j1]; s5/s6 Wpy[j0/j1->u].
// Per slot, half index = ((et*8 + kc)*64 + lane)*8 + h, where
// e = et*16 + (lane&15), k = kc*32 + (lane>>4)*8 + h. A wave's bf fragment
// load is then 1KB contiguous.
// ---------------------------------------------------------------------------
__global__ __launch_bounds__(256) void convw_kernel(
    const float* __restrict__ Wu, const float* __restrict__ Wsx, const float* __restrict__ Wsy,
    const float* __restrict__ Wpx, const float* __restrict__ Wpy, float* __restrict__ ws)
{
    const int slot = blockIdx.x;          // 0..20
    const int kc   = blockIdx.y;          // 0..7
    const int tid  = threadIdx.x;
    const int u = slot / 7, s = slot % 7;
    const int j0 = (u==0)?1:0, j1 = (u==2)?1:2;
    const float* W =
        s==0 ? Wu  + (size_t)u*DD*DD :
        s==1 ? Wsx + (size_t)u*DD*DD :
        s==2 ? Wsy + (size_t)u*DD*DD :
        s==3 ? Wpx + (size_t)(u*NU+j0)*DD*DD :
        s==4 ? Wpx + (size_t)(u*NU+j1)*DD*DD :
        s==5 ? Wpy + (size_t)(j0*NU+u)*DD*DD :
               Wpy + (size_t)(j1*NU+u)*DD*DD;
    _Float16* wh = (_Float16*)(ws + WS_FLOATS) + (size_t)slot*65536;
    #pragma unroll
    for (int g = 0; g < 4; ++g) {
        const int idx16 = g*256 + tid;        // 0..1023 = et*64 + lane
        const int et   = idx16 >> 6;
        const int lane = idx16 & 63;
        const int e  = et*16 + (lane & 15);
        const int k0 = kc*32 + (lane >> 4)*8;
        const float* sp = W + (size_t)e*DD + k0;
        const float4 v0 = *reinterpret_cast<const float4*>(sp);
        const float4 v1 = *reinterpret_cast<const float4*>(sp + 4);
        *reinterpret_cast<half8*>(wh + ((size_t)(et*8 + kc)*64 + lane)*8) = cvt8(v0, v1);
    }
}

// ---------------------------------------------------------------------------
// Pass 1: grid (MM/64, 3). Block = 64-token tile of util u, 4 waves; wave wq
// owns e in [wq*64, wq*64+64). U tile f16 LDS (XOR-swizzled); A m=0,1
// register-resident, m=2,3 from LDS per slab. W streamed global->register
// with THREE buffers at ISSUE DISTANCE 2 (8KB/wave in flight) — the depth-1
// pipeline of rounds 4-10 left each wave exposed to full loaded VMEM latency
// every slab (the ~100us invariant). K-loop barrier-free; 7 tasks, fused
// epilogues; buffer rotation period 3 over tasks.
// ---------------------------------------------------------------------------
__global__ __launch_bounds__(256, 3) void pass1_kernel(
    const float* __restrict__ u0, const float* __restrict__ u1, const float* __restrict__ u2,
    const float* __restrict__ bu, const float* __restrict__ wr, const float* __restrict__ br,
    const float* __restrict__ bsx, const float* __restrict__ bsy,
    const float* __restrict__ bpx, const float* __restrict__ bpy,
    float* __restrict__ ws)
{
    __shared__ __align__(16) _Float16 Ub[16384];   // [kc=8][tok=64][32k] swizzled
    __shared__ float ep_sum[4][64];
    __shared__ float ep_inv[64];

    const int tid  = threadIdx.x;
    const int u    = blockIdx.y;
    const int row0 = blockIdx.x * 64;
    const int b    = row0 >> 10;

    const int j0 = (u==0)?1:0, j1 = (u==2)?1:2;
    const int px0 = u*2, px1 = u*2+1;
    const int py0 = (u==0)?2:((u==1)?0:1);
    const int py1 = (u==0)?4:((u==1)?5:3);

    const float* src = selU(u,u0,u1,u2);
    const _Float16* whU = (const _Float16*)(ws + WS_FLOATS) + (size_t)u*7*65536;

    const int lane = tid & 63, wq = tid >> 6;
    const int l15 = lane & 15, lg = lane >> 4;
    const int swz = (l15 >> 1) & 3;
    const int kxor = (lg ^ swz) * 8;

    // per-wave W base: fragment (n,kc) at wbase + s*65536 + n*4096 + kc*512
    const _Float16* wbase = whU + (size_t)wq*16384 + (size_t)lane*8;

    f32x4 acc[4][4];
    #pragma unroll
    for (int m = 0; m < 4; ++m)
        #pragma unroll
        for (int n = 0; n < 4; ++n) acc[m][n] = (f32x4)0.f;

    half8 bf0[4], bf1[4], bf2[4];
    half8 af_res[2][8];

#define BFLD(DST, S, KC) { \
    _Pragma("unroll") \
    for (int n_ = 0; n_ < 4; ++n_) \
        DST[n_] = *reinterpret_cast<const half8*>(wbase + (size_t)(S)*65536 + n_*4096 + (KC)*512); }

// compute slab KC from CUR; issue fragment (IS_S, IS_KC) into ISS (distance 2)
#define SLAB(KC, CUR, ISS, IS_S, IS_KC) { \
    if ((IS_S) < 7) { BFLD(ISS, (IS_S), (IS_KC)) } \
    half8 afd0 = *reinterpret_cast<const half8*>(&Ub[(KC)*2048 + (32 + l15)*32 + kxor]); \
    half8 afd1 = *reinterpret_cast<const half8*>(&Ub[(KC)*2048 + (48 + l15)*32 + kxor]); \
    _Pragma("unroll") \
    for (int n_ = 0; n_ < 4; ++n_) { \
        acc[0][n_] = __builtin_amdgcn_mfma_f32_16x16x32_f16(af_res[0][KC], CUR[n_], acc[0][n_],0,0,0); \
        acc[1][n_] = __builtin_amdgcn_mfma_f32_16x16x32_f16(af_res[1][KC], CUR[n_], acc[1][n_],0,0,0); } \
    _Pragma("unroll") \
    for (int n_ = 0; n_ < 4; ++n_) { \
        acc[2][n_] = __builtin_amdgcn_mfma_f32_16x16x32_f16(afd0, CUR[n_], acc[2][n_],0,0,0); \
        acc[3][n_] = __builtin_amdgcn_mfma_f32_16x16x32_f16(afd1, CUR[n_], acc[3][n_],0,0,0); } }

// 8 slabs of task s with rotation (P=slab0, Q=slab1, R=slab2)
#define TASK8(P, Q, R) \
    SLAB(0, P, R, s,   2) \
    SLAB(1, Q, P, s,   3) \
    SLAB(2, R, Q, s,   4) \
    SLAB(3, P, R, s,   5) \
    SLAB(4, Q, P, s,   6) \
    SLAB(5, R, Q, s,   7) \
    SLAB(6, P, R, s+1, 0) \
    SLAB(7, Q, P, s+1, 1)

    // prologue: issue slabs (0,0),(0,1) early (hide under U staging)
    BFLD(bf0, 0, 0)
    BFLD(bf1, 0, 1)

    // U prologue: 64 tok x 256 k fp32 -> f16 swizzled LDS (once per block)
    #pragma unroll
    for (int c = 0; c < 8; ++c) {
        const int G2 = c*256 + tid;          // 0..2047
        const int t  = G2 >> 5;              // token 0..63
        const int gk = G2 & 31;              // k-granule 0..31
        const int kc = gk >> 2, kg = gk & 3;
        const float* p = src + (size_t)(row0 + t)*DD + gk*8;
        const float4 v0 = *reinterpret_cast<const float4*>(p);
        const float4 v1 = *reinterpret_cast<const float4*>(p + 4);
        const int kgs = kg ^ ((t >> 1) & 3);
        *reinterpret_cast<half8*>(&Ub[kc*2048 + t*32 + kgs*8]) = cvt8(v0, v1);
    }
    __syncthreads();

    // register-resident A fragments (m=0,1) for all kc
    #pragma unroll
    for (int kc = 0; kc < 8; ++kc) {
        af_res[0][kc] = *reinterpret_cast<const half8*>(&Ub[kc*2048 + (l15)*32 + kxor]);
        af_res[1][kc] = *reinterpret_cast<const half8*>(&Ub[kc*2048 + (16 + l15)*32 + kxor]);
    }

    for (int s = 0; s < 7; ++s) {
        const int rot = s % 3;   // buffer rotation: slab0 lives in bf[(3 - 2s) mod 3]
        if (rot == 0)      { TASK8(bf0, bf1, bf2) }
        else if (rot == 1) { TASK8(bf2, bf0, bf1) }
        else               { TASK8(bf1, bf2, bf0) }

        // ================= epilogue for task s =================
        const float* bias =
            s==0 ? bu  + u*DD :
            s==1 ? bsx + u*DD :
            s==2 ? bsy + u*DD :
            s==3 ? bpx + (u*NU+j0)*DD :
            s==4 ? bpx + (u*NU+j1)*DD :
            s==5 ? bpy + (j0*NU+u)*DD :
                   bpy + (j1*NU+u)*DD;
        float bv[4];
        #pragma unroll
        for (int n = 0; n < 4; ++n) bv[n] = bias[wq*64 + n*16 + l15];
        #pragma unroll
        for (int m = 0; m < 4; ++m)
            #pragma unroll
            for (int n = 0; n < 4; ++n)
                #pragma unroll
                for (int r = 0; r < 4; ++r) acc[m][n][r] += bv[n];

        if (s == 0) {
            float wrv[4];
            #pragma unroll
            for (int n = 0; n < 4; ++n) wrv[n] = wr[u*DD + wq*64 + n*16 + l15];
            float pm[4][4];
            #pragma unroll
            for (int m = 0; m < 4; ++m)
                #pragma unroll
                for (int r = 0; r < 4; ++r) {
                    float t = 0.f;
                    #pragma unroll
                    for (int n = 0; n < 4; ++n) t = fmaf(fmaxf(acc[m][n][r], 0.f), wrv[n], t);
                    pm[m][r] = t;
                }
            #pragma unroll
            for (int mask = 1; mask <= 8; mask <<= 1)
                #pragma unroll
                for (int m = 0; m < 4; ++m)
                    #pragma unroll
                    for (int r = 0; r < 4; ++r) pm[m][r] += __shfl_xor(pm[m][r], mask);
            if (l15 == 0) {
                #pragma unroll
                for (int m = 0; m < 4; ++m)
                    #pragma unroll
                    for (int r = 0; r < 4; ++r) ep_sum[wq][m*16 + lg*4 + r] = pm[m][r];
            }
            __syncthreads();
            if (tid < 64)
                ws[OFF_UNARY + (size_t)u*MM + row0 + tid] =
                    ep_sum[0][tid]+ep_sum[1][tid]+ep_sum[2][tid]+ep_sum[3][tid] + br[u];
        } else {
            float pm[4][4];
            #pragma unroll
            for (int m = 0; m < 4; ++m)
                #pragma unroll
                for (int r = 0; r < 4; ++r) {
                    float t = 0.f;
                    #pragma unroll
                    for (int n = 0; n < 4; ++n) t = fmaf(acc[m][n][r], acc[m][n][r], t);
                    pm[m][r] = t;
                }
            #pragma unroll
            for (int mask = 1; mask <= 8; mask <<= 1)
                #pragma unroll
                for (int m = 0; m < 4; ++m)
                    #pragma unroll
                    for (int r = 0; r < 4; ++r) pm[m][r] += __shfl_xor(pm[m][r], mask);
            if (l15 == 0) {
                #pragma unroll
                for (int m = 0; m < 4; ++m)
                    #pragma unroll
                    for (int r = 0; r < 4; ++r) ep_sum[wq][m*16 + lg*4 + r] = pm[m][r];
            }
            __syncthreads();
            if (tid < 64) {
                const float ssum = ep_sum[0][tid]+ep_sum[1][tid]+ep_sum[2][tid]+ep_sum[3][tid];
                const float inv = 1.f / fmaxf(sqrtf(ssum), 1e-12f);
                ep_inv[tid] = inv;
                if (s == 1)      ws[OFF_INVXS + (size_t)u  *MM + row0 + tid] = inv;
                else if (s == 3) ws[OFF_INVXP + (size_t)px0*MM + row0 + tid] = inv;
                else if (s == 4) ws[OFF_INVXP + (size_t)px1*MM + row0 + tid] = inv;
                else if (s == 5) ws[OFF_INVYP + (size_t)py0*MM + row0 + tid] = inv;
                else if (s == 6) ws[OFF_INVYP + (size_t)py1*MM + row0 + tid] = inv;
            }
            __syncthreads();
            if (s >= 2) {
                float invv[4][4];
                #pragma unroll
                for (int m = 0; m < 4; ++m)
                    #pragma unroll
                    for (int r = 0; r < 4; ++r) invv[m][r] = ep_inv[m*16 + lg*4 + r];
                float qn[4];
                #pragma unroll
                for (int n = 0; n < 4; ++n) {
                    float t = 0.f;
                    #pragma unroll
                    for (int m = 0; m < 4; ++m)
                        #pragma unroll
                        for (int r = 0; r < 4; ++r) t = fmaf(acc[m][n][r], invv[m][r], t);
                    qn[n] = t;
                }
                #pragma unroll
                for (int n = 0; n < 4; ++n) {
                    qn[n] += __shfl_xor(qn[n], 16);
                    qn[n] += __shfl_xor(qn[n], 32);
                }
                float* bar =
                    s==2 ? ws + OFF_YBAR  + ((size_t)u  *BB + b)*DD :
                    s==3 ? ws + OFF_XPBAR + ((size_t)px0*BB + b)*DD :
                    s==4 ? ws + OFF_XPBAR + ((size_t)px1*BB + b)*DD :
                    s==5 ? ws + OFF_YPBAR + ((size_t)py0*BB + b)*DD :
                           ws + OFF_YPBAR + ((size_t)py1*BB + b)*DD;
                if (lane < 16) {
                    #pragma unroll
                    for (int n = 0; n < 4; ++n)
                        atomicAdd(&bar[wq*64 + n*16 + lane], qn[n]);
                }
            }
        }
        #pragma unroll
        for (int m = 0; m < 4; ++m)
            #pragma unroll
            for (int n = 0; n < 4; ++n) acc[m][n] = (f32x4)0.f;
        __syncthreads();   // protect ep_sum/ep_inv reuse next task
    }
#undef BFLD
#undef SLAB
#undef TASK8
}

// ---------------------------------------------------------------------------
// Pass 2a: proj[d] = sum_e W[e][d] * (bar[e]/N);  cs = sum_e bias[e]*(bar[e]/N)
// ---------------------------------------------------------------------------
__global__ __launch_bounds__(256) void proj_kernel(
    const float* __restrict__ Wsx, const float* __restrict__ bsx,
    const float* __restrict__ Wpx, const float* __restrict__ bpx,
    const float* __restrict__ Wpy, const float* __restrict__ bpy,
    float* __restrict__ ws)
{
    __shared__ float barl[DD];
    __shared__ float redl[256];
    const int task = blockIdx.x >> 4;
    const int b    = blockIdx.x & 15;
    const int tid  = threadIdx.x;
    const float *W, *bias, *barp;
    float *projp, *csp;
    if (task < 3) {
        const int uu = task;
        W = Wsx + (size_t)uu*DD*DD; bias = bsx + uu*DD;
        barp  = ws + OFF_YBAR  + ((size_t)uu*BB + b)*DD;
        projp = ws + OFF_PROJS + ((size_t)uu*BB + b)*DD;
        csp   = ws + OFF_CSS + uu*BB + b;
    } else if (task < 9) {
        const int p = task - 3; const int i = p>>1;
        const int j = (p&1) == 0 ? (i==0?1:0) : (i==2?1:2);
        W = Wpx + (size_t)(i*NU+j)*DD*DD; bias = bpx + (i*NU+j)*DD;
        barp  = ws + OFF_YPBAR + ((size_t)p*BB + b)*DD;
        projp = ws + OFF_PROJX + ((size_t)p*BB + b)*DD;
        csp   = ws + OFF_CSX + p*BB + b;
    } else {
        const int p = task - 9; const int i = p>>1;
        const int j = (p&1) == 0 ? (i==0?1:0) : (i==2?1:2);
        W = Wpy + (size_t)(i*NU+j)*DD*DD; bias = bpy + (i*NU+j)*DD;
        barp  = ws + OFF_XPBAR + ((size_t)p*BB + b)*DD;
        projp = ws + OFF_PROJY + ((size_t)p*BB + b)*DD;
        csp   = ws + OFF_CSY + p*BB + b;
    }
    barl[tid] = barp[tid] * (1.f / NN);
    __syncthreads();
    float s = 0.f;
    for (int e = 0; e < DD; ++e) s = fmaf(W[(size_t)e*DD + tid], barl[e], s);
    projp[tid] = s;
    redl[tid] = bias[tid] * barl[tid];
    __syncthreads();
    for (int st = 128; st > 0; st >>= 1) {
        if (tid < st) redl[tid] += redl[tid + st];
        __syncthreads();
    }
    if (tid == 0) *csp = redl[0];
}

// ---------------------------------------------------------------------------
// Pass 2b (util-fused): per 32-token tile of util u, dot U rows against the
// 5 proj vectors that have u as source; write 5 potential arrays.
// ---------------------------------------------------------------------------
__global__ __launch_bounds__(256) void pots_kernel(
    const float* __restrict__ u0, const float* __restrict__ u1, const float* __restrict__ u2,
    float* __restrict__ ws)
{
    __shared__ float projl[5][DD];
    __shared__ float csl[5];
    const int u    = blockIdx.y;
    const int row0 = blockIdx.x * 32;
    const int b    = row0 >> 10;
    const int tid  = threadIdx.x;
    const int px0 = u*2, px1 = u*2+1;
    const int py0 = (u==0)?2:((u==1)?0:1);
    const int py1 = (u==0)?4:((u==1)?5:3);

    projl[0][tid] = ws[OFF_PROJS + ((size_t)u  *BB + b)*DD + tid];
    projl[1][tid] = ws[OFF_PROJX + ((size_t)px0*BB + b)*DD + tid];
    projl[2][tid] = ws[OFF_PROJX + ((size_t)px1*BB + b)*DD + tid];
    projl[3][tid] = ws[OFF_PROJY + ((size_t)py0*BB + b)*DD + tid];
    projl[4][tid] = ws[OFF_PROJY + ((size_t)py1*BB + b)*DD + tid];
    if (tid == 0) {
        csl[0] = ws[OFF_CSS + u*BB + b];
        csl[1] = ws[OFF_CSX + px0*BB + b];
        csl[2] = ws[OFF_CSX + px1*BB + b];
        csl[3] = ws[OFF_CSY + py0*BB + b];
        csl[4] = ws[OFF_CSY + py1*BB + b];
    }
    __syncthreads();
    const float* src = selU(u,u0,u1,u2);
    const int token = tid >> 3, q = tid & 7;
    const int row = row0 + token;
    float a0=0.f,a1=0.f,a2=0.f,a3=0.f,a4=0.f;
    #pragma unroll
    for (int cc = 0; cc < 8; ++cc) {
        const int d0 = q*32 + cc*4;
        const float4 v  = *reinterpret_cast<const float4*>(src + (size_t)row*DD + d0);
        const float4 p0 = *reinterpret_cast<const float4*>(&projl[0][d0]);
        const float4 p1 = *reinterpret_cast<const float4*>(&projl[1][d0]);
        const float4 p2 = *reinterpret_cast<const float4*>(&projl[2][d0]);
        const float4 p3 = *reinterpret_cast<const float4*>(&projl[3][d0]);
        const float4 p4 = *reinterpret_cast<const float4*>(&projl[4][d0]);
        a0 = fmaf(v.x,p0.x,fmaf(v.y,p0.y,fmaf(v.z,p0.z,fmaf(v.w,p0.w,a0))));
        a1 = fmaf(v.x,p1.x,fmaf(v.y,p1.y,fmaf(v.z,p1.z,fmaf(v.w,p1.w,a1))));
        a2 = fmaf(v.x,p2.x,fmaf(v.y,p2.y,fmaf(v.z,p2.z,fmaf(v.w,p2.w,a2))));
        a3 = fmaf(v.x,p3.x,fmaf(v.y,p3.y,fmaf(v.z,p3.z,fmaf(v.w,p3.w,a3))));
        a4 = fmaf(v.x,p4.x,fmaf(v.y,p4.y,fmaf(v.z,p4.z,fmaf(v.w,p4.w,a4))));
    }
    #pragma unroll
    for (int mask = 1; mask <= 4; mask <<= 1) {
        a0 += __shfl_xor(a0, mask, 8);
        a1 += __shfl_xor(a1, mask, 8);
        a2 += __shfl_xor(a2, mask, 8);
        a3 += __shfl_xor(a3, mask, 8);
        a4 += __shfl_xor(a4, mask, 8);
    }
    if (q == 0) {
        ws[OFF_SELFP + (size_t)u  *MM + row] = (a0 + csl[0]) * ws[OFF_INVXS + (size_t)u  *MM + row];
        ws[OFF_POTX  + (size_t)px0*MM + row] = (a1 + csl[1]) * ws[OFF_INVXP + (size_t)px0*MM + row];
        ws[OFF_POTX  + (size_t)px1*MM + row] = (a2 + csl[2]) * ws[OFF_INVXP + (size_t)px1*MM + row];
        ws[OFF_POTY  + (size_t)py0*MM + row] = (a3 + csl[3]) * ws[OFF_INVYP + (size_t)py0*MM + row];
        ws[OFF_POTY  + (size_t)py1*MM + row] = (a4 + csl[4]) * ws[OFF_INVYP + (size_t)py1*MM + row];
    }
}

// ---------------------------------------------------------------------------
// Pass 3a: per (j,b): logits for i=0..2 -> softmax -> normalized probs to ws
// ---------------------------------------------------------------------------
__global__ __launch_bounds__(256) void attend_logits_kernel(
    const float* __restrict__ wdiag, const float* __restrict__ wpair,
    float* __restrict__ ws)
{
    __shared__ float el[3][NN];
    __shared__ float redl[256];
    const int c = blockIdx.x;          // 0..47
    const int j = c >> 4, b = c & 15;
    const int tid = threadIdx.x;

    #pragma unroll
    for (int i = 0; i < 3; ++i) {
        if (i == j) {
            const int p1 = i*2, p2 = i*2+1;
            const float w0 = wdiag[i*4+0], w1 = wdiag[i*4+1], w2 = wdiag[i*4+2], w3 = wdiag[i*4+3];
            for (int n = tid; n < NN; n += 256) {
                const int row = b*NN + n;
                el[i][n] = w0*ws[OFF_UNARY + i*MM + row] + w1*ws[OFF_SELFP + i*MM + row]
                         + w2*ws[OFF_POTX + p1*MM + row] + w3*ws[OFF_POTX + p2*MM + row];
            }
        } else {
            const int p = i*2 + (j > i ? j-1 : j);
            const float w0 = wpair[(i*3+j)*3+0], w1 = wpair[(i*3+j)*3+1], w2 = wpair[(i*3+j)*3+2];
            for (int n = tid; n < NN; n += 256) {
                const int row = b*NN + n;
                el[i][n] = w0*ws[OFF_UNARY + j*MM + row] + w1*ws[OFF_SELFP + j*MM + row]
                         + w2*ws[OFF_POTY + p*MM + row];
            }
        }
    }
    __syncthreads();
    #pragma unroll
    for (int i = 0; i < 3; ++i) {
        float m = -1e30f;
        for (int n = tid; n < NN; n += 256) m = fmaxf(m, el[i][n]);
        redl[tid] = m; __syncthreads();
        for (int st = 128; st > 0; st >>= 1) {
            if (tid < st) redl[tid] = fmaxf(redl[tid], redl[tid+st]);
            __syncthreads();
        }
        m = redl[0];
        __syncthreads();
        float ss = 0.f;
        for (int n = tid; n < NN; n += 256) {
            const float e = expf(el[i][n] - m);
            el[i][n] = e;
            ss += e;
        }
        redl[tid] = ss; __syncthreads();
        for (int st = 128; st > 0; st >>= 1) {
            if (tid < st) redl[tid] += redl[tid+st];
            __syncthreads();
        }
        const float invS = 1.f / redl[0];
        __syncthreads();
        for (int n = tid; n < NN; n += 256)
            ws[OFF_PROB + ((size_t)(i*3+j)*BB + b)*NN + n] = el[i][n] * invS;
    }
}

// ---------------------------------------------------------------------------
// Pass 3b: chunked weighted sum: partial[(i,j,b)][chunk][d]
// ---------------------------------------------------------------------------
__global__ __launch_bounds__(256) void attend_sum_kernel(
    const float* __restrict__ u0, const float* __restrict__ u1, const float* __restrict__ u2,
    const float* __restrict__ ws, float* __restrict__ wso)
{
    __shared__ float pl[3][128];
    const int x  = blockIdx.x;         // 0..383
    const int jb = x >> 3, ch = x & 7;
    const int j = jb >> 4, b = jb & 15;
    const int tid = threadIdx.x;

    for (int t = tid; t < 384; t += 256) {
        const int i = t >> 7, n = t & 127;
        pl[i][n] = ws[OFF_PROB + ((size_t)(i*3+j)*BB + b)*NN + ch*128 + n];
    }
    __syncthreads();
    const float* Uj = selU(j, u0, u1, u2) + ((size_t)b*NN + ch*128)*DD;
    float a0 = 0.f, a1 = 0.f, a2 = 0.f;
    #pragma unroll 4
    for (int n = 0; n < 128; ++n) {
        const float v = Uj[(size_t)n*DD + tid];
        a0 = fmaf(pl[0][n], v, a0);
        a1 = fmaf(pl[1][n], v, a1);
        a2 = fmaf(pl[2][n], v, a2);
    }
    wso[OFF_PART + (((size_t)(0*3+j)*BB + b)*8 + ch)*DD + tid] = a0;
    wso[OFF_PART + (((size_t)(1*3+j)*BB + b)*8 + ch)*DD + tid] = a1;
    wso[OFF_PART + (((size_t)(2*3+j)*BB + b)*8 + ch)*DD + tid] = a2;
}

// ---------------------------------------------------------------------------
// Pass 3c: reduce chunks -> out
// ---------------------------------------------------------------------------
__global__ __launch_bounds__(256) void attend_reduce_kernel(
    const float* __restrict__ ws, float* __restrict__ out)
{
    const int ijb = blockIdx.x;        // 0..143
    const int tid = threadIdx.x;
    float s = 0.f;
    #pragma unroll
    for (int ch = 0; ch < 8; ++ch)
        s += ws[OFF_PART + ((size_t)ijb*8 + ch)*DD + tid];
    out[(size_t)ijb*DD + tid] = s;
}

// ---------------------------------------------------------------------------
extern "C" void kernel_launch(void* const* d_in, const int* in_sizes, int n_in,
                              void* d_out, int out_size, void* d_ws, size_t ws_size,
                              hipStream_t stream)
{
    (void)in_sizes; (void)n_in; (void)out_size; (void)ws_size;
    const float* u0    = (const float*)d_in[0];
    const float* u1    = (const float*)d_in[1];
    const float* u2    = (const float*)d_in[2];
    const float* Wu    = (const float*)d_in[3];
    const float* bu    = (const float*)d_in[4];
    const float* wr    = (const float*)d_in[5];
    const float* br    = (const float*)d_in[6];
    const float* Wsx   = (const float*)d_in[7];
    const float* bsx   = (const float*)d_in[8];
    const float* Wsy   = (const float*)d_in[9];
    const float* bsy   = (const float*)d_in[10];
    const float* Wpx   = (const float*)d_in[11];
    const float* bpx   = (const float*)d_in[12];
    const float* Wpy   = (const float*)d_in[13];
    const float* bpy   = (const float*)d_in[14];
    const float* wdiag = (const float*)d_in[15];
    const float* wpair = (const float*)d_in[16];
    float* ws  = (float*)d_ws;
    float* out = (float*)d_out;

    // zero the atomic accumulators (Ybar, Xpbar, Ypbar are contiguous)
    hipMemsetAsync(ws + OFF_YBAR, 0, (size_t)(NU + 2*NPAIR)*BB*DD*sizeof(float), stream);

    dim3 gw(21, 8);
    convw_kernel<<<gw, 256, 0, stream>>>(Wu, Wsx, Wsy, Wpx, Wpy, ws);

    dim3 g1(MM/64, 3);
    pass1_kernel<<<g1, 256, 0, stream>>>(u0,u1,u2,bu,wr,br,bsx,bsy,bpx,bpy,ws);

    proj_kernel<<<15*BB, 256, 0, stream>>>(Wsx,bsx,Wpx,bpx,Wpy,bpy,ws);
    dim3 g2(MM/32, 3);
    pots_kernel<<<g2, 256, 0, stream>>>(u0,u1,u2,ws);

    attend_logits_kernel<<<3*BB, 256, 0, stream>>>(wdiag, wpair, ws);
    attend_sum_kernel<<<3*BB*8, 256, 0, stream>>>(u0,u1,u2, ws, ws);
    attend_reduce_kernel<<<9*BB, 256, 0, stream>>>(ws, out);
}

// Round 12
// 154.494 us; speedup vs baseline: 1.6901x; 1.6901x over previous
//
#include <hip/hip_runtime.h>
#include <math.h>

#define NU 3
#define BB 16
#define NN 1024
#define DD 256
#define MM (BB*NN)      // 16384 tokens per util
#define NPAIR 6

// workspace layout (float element offsets)
#define OFF_UNARY  0
#define OFF_INVXS  (OFF_UNARY + NU*MM)
#define OFF_INVXP  (OFF_INVXS + NU*MM)
#define OFF_INVYP  (OFF_INVXP + NPAIR*MM)
#define OFF_YBAR   (OFF_INVYP + NPAIR*MM)          // bars contiguous for one memset
#define OFF_XPBAR  (OFF_YBAR + NU*BB*DD)
#define OFF_YPBAR  (OFF_XPBAR + NPAIR*BB*DD)
#define OFF_PROJS  (OFF_YPBAR + NPAIR*BB*DD)
#define OFF_PROJX  (OFF_PROJS + NU*BB*DD)
#define OFF_PROJY  (OFF_PROJX + NPAIR*BB*DD)
#define OFF_CSS    (OFF_PROJY + NPAIR*BB*DD)
#define OFF_CSX    (OFF_CSS + NU*BB)
#define OFF_CSY    (OFF_CSX + NPAIR*BB)
#define OFF_SELFP  (OFF_CSY + NPAIR*BB)
#define OFF_POTX   (OFF_SELFP + NU*MM)
#define OFF_POTY   (OFF_POTX + NPAIR*MM)
#define WS_FLOATS  (OFF_POTY + NPAIR*MM)           // = 663792
// f16 weights, LDS-image order: 21 slots x 65536 halves = 688128 floats
#define OFF_PROB   (WS_FLOATS + 21*32768)
#define OFF_PART   (OFF_PROB + 9*BB*NN)
// end = OFF_PART + 9*BB*8*DD  (~7.2 MB total)

typedef _Float16 half8 __attribute__((ext_vector_type(8)));
typedef float f32x4 __attribute__((ext_vector_type(4)));

__device__ __forceinline__ const float* selU(int u, const float* u0, const float* u1, const float* u2) {
    return u == 0 ? u0 : (u == 1 ? u1 : u2);
}
__device__ __forceinline__ half8 cvt8(float4 a, float4 b) {
    half8 h = { (_Float16)a.x,(_Float16)a.y,(_Float16)a.z,(_Float16)a.w,
                (_Float16)b.x,(_Float16)b.y,(_Float16)b.z,(_Float16)b.w };
    return h;
}
// async global->LDS 16B copy: LDS dest is wave-uniform base + lane*16,
// global src is per-lane. The compiler never auto-emits this path.
__device__ __forceinline__ void gload16(const _Float16* g, _Float16* l) {
    __builtin_amdgcn_global_load_lds(
        (const __attribute__((address_space(1))) void*)g,
        (__attribute__((address_space(3))) void*)l,
        16, 0, 0);
}

// ---------------------------------------------------------------------------
// Weight convert: fp32 -> f16, LDS-image order. Slot (u, s=0..6):
// s0 Wu[u]; s1 Wsx[u]; s2 Wsy[u]; s3/s4 Wpx[u->j0/j1]; s5/s6 Wpy[j0/j1->u].
// Per slot: [kc=0..7][et=0..15][lane=0..63][h=0..7] where e = et*16+(lane&15),
// k = kc*32+(lane>>4)*8+h. Each (slot,kc) 16KB chunk is the exact LDS image
// pass1 stages with global_load_lds (contiguous, pre-fragmented).
// ---------------------------------------------------------------------------
__global__ __launch_bounds__(256) void convw_kernel(
    const float* __restrict__ Wu, const float* __restrict__ Wsx, const float* __restrict__ Wsy,
    const float* __restrict__ Wpx, const float* __restrict__ Wpy, float* __restrict__ ws)
{
    const int slot = blockIdx.x;          // 0..20
    const int kc   = blockIdx.y;          // 0..7
    const int tid  = threadIdx.x;
    const int u = slot / 7, s = slot % 7;
    const int j0 = (u==0)?1:0, j1 = (u==2)?1:2;
    const float* W =
        s==0 ? Wu  + (size_t)u*DD*DD :
        s==1 ? Wsx + (size_t)u*DD*DD :
        s==2 ? Wsy + (size_t)u*DD*DD :
        s==3 ? Wpx + (size_t)(u*NU+j0)*DD*DD :
        s==4 ? Wpx + (size_t)(u*NU+j1)*DD*DD :
        s==5 ? Wpy + (size_t)(j0*NU+u)*DD*DD :
               Wpy + (size_t)(j1*NU+u)*DD*DD;
    _Float16* wh = (_Float16*)(ws + WS_FLOATS) + (size_t)slot*65536 + (size_t)kc*8192;
    #pragma unroll
    for (int g = 0; g < 4; ++g) {
        const int idx16 = g*256 + tid;        // 0..1023 = et*64 + lane
        const int lane = idx16 & 63;
        const int e  = (idx16 >> 6)*16 + (lane & 15);
        const int k0 = kc*32 + (lane >> 4)*8;
        const float* sp = W + (size_t)e*DD + k0;
        const float4 v0 = *reinterpret_cast<const float4*>(sp);
        const float4 v1 = *reinterpret_cast<const float4*>(sp + 4);
        *reinterpret_cast<half8*>(wh + (size_t)idx16*8) = cvt8(v0, v1);
    }
}

// ---------------------------------------------------------------------------
// Pass 1: grid (MM/64, 3). Block = 64-token tile of util u, 4 waves; wave wq
// owns e in [wq*64, wq*64+64). U tile f16 LDS-resident (XOR-swizzled, staged
// once). B streamed via async global_load_lds dwordx4 into double-buffered
// LDS slabs (2 x 16KB) — zero staging registers, zero staging VALU; each
// wave issues 4 async copies per 32-K step. One barrier per step; 56 steps;
// fused per-task epilogues.
// ---------------------------------------------------------------------------
__global__ __launch_bounds__(256, 2) void pass1_kernel(
    const float* __restrict__ u0, const float* __restrict__ u1, const float* __restrict__ u2,
    const float* __restrict__ bu, const float* __restrict__ wr, const float* __restrict__ br,
    const float* __restrict__ bsx, const float* __restrict__ bsy,
    const float* __restrict__ bpx, const float* __restrict__ bpy,
    float* __restrict__ ws)
{
    __shared__ __align__(16) _Float16 Ub[16384];     // [kc=8][tok=64][32k] swizzled (32 KB)
    __shared__ __align__(16) _Float16 Wb[2][8192];   // dbuf x [et=16][lane=64][h=8] (2x16 KB)
    __shared__ float ep_sum[4][64];
    __shared__ float ep_inv[64];

    const int tid  = threadIdx.x;
    const int u    = blockIdx.y;
    const int row0 = blockIdx.x * 64;
    const int b    = row0 >> 10;

    const int j0 = (u==0)?1:0, j1 = (u==2)?1:2;
    const int px0 = u*2, px1 = u*2+1;
    const int py0 = (u==0)?2:((u==1)?0:1);
    const int py1 = (u==0)?4:((u==1)?5:3);

    const float* src = selU(u,u0,u1,u2);
    const _Float16* whU = (const _Float16*)(ws + WS_FLOATS) + (size_t)u*7*65536;

    const int lane = tid & 63, wq = tid >> 6;
    const int l15 = lane & 15, lg = lane >> 4;
    const int swz = (l15 >> 1) & 3;
    const int kxor = (lg ^ swz) * 8;

    f32x4 acc[4][4];
    #pragma unroll
    for (int m = 0; m < 4; ++m)
        #pragma unroll
        for (int n = 0; n < 4; ++n) acc[m][n] = (f32x4)0.f;

// stage B slab t (= task*8 + kc) into Wb[BUF]: 4 async 1KB copies per wave
#define STAGE(T, BUF) { \
    const _Float16* gsb = whU + (size_t)((T) >> 3)*65536 + (size_t)((T) & 7)*8192 \
                        + (size_t)(wq*4)*512 + (size_t)lane*8; \
    _Pragma("unroll") \
    for (int i_ = 0; i_ < 4; ++i_) \
        gload16(gsb + i_*512, &Wb[BUF][(wq*4 + i_)*512]); }

    // prologue: stage slab 0 into buf 0 (lands during U staging)
    STAGE(0, 0)

    // U prologue: 64 tok x 256 k fp32 -> f16 swizzled LDS (once per block)
    #pragma unroll
    for (int c = 0; c < 8; ++c) {
        const int G2 = c*256 + tid;          // 0..2047
        const int t  = G2 >> 5;              // token 0..63
        const int gk = G2 & 31;              // k-granule 0..31
        const int kc = gk >> 2, kg = gk & 3;
        const float* p = src + (size_t)(row0 + t)*DD + gk*8;
        const float4 v0 = *reinterpret_cast<const float4*>(p);
        const float4 v1 = *reinterpret_cast<const float4*>(p + 4);
        const int kgs = kg ^ ((t >> 1) & 3);
        *reinterpret_cast<half8*>(&Ub[kc*2048 + t*32 + kgs*8]) = cvt8(v0, v1);
    }
    __syncthreads();   // drains U ds_writes AND slab-0 async copies

    for (int s = 0; s < 7; ++s) {
        #pragma unroll
        for (int kc = 0; kc < 8; ++kc) {
            const int t = s*8 + kc;
            const int cur = t & 1;
            if (t < 55) STAGE(t+1, cur^1)
            half8 af0 = *reinterpret_cast<const half8*>(&Ub[kc*2048 + (     l15)*32 + kxor]);
            half8 af1 = *reinterpret_cast<const half8*>(&Ub[kc*2048 + (16 + l15)*32 + kxor]);
            half8 af2 = *reinterpret_cast<const half8*>(&Ub[kc*2048 + (32 + l15)*32 + kxor]);
            half8 af3 = *reinterpret_cast<const half8*>(&Ub[kc*2048 + (48 + l15)*32 + kxor]);
            #pragma unroll
            for (int n = 0; n < 4; ++n) {
                const half8 bf = *reinterpret_cast<const half8*>(&Wb[cur][(wq*4 + n)*512 + lane*8]);
                acc[0][n] = __builtin_amdgcn_mfma_f32_16x16x32_f16(af0, bf, acc[0][n],0,0,0);
                acc[1][n] = __builtin_amdgcn_mfma_f32_16x16x32_f16(af1, bf, acc[1][n],0,0,0);
                acc[2][n] = __builtin_amdgcn_mfma_f32_16x16x32_f16(af2, bf, acc[2][n],0,0,0);
                acc[3][n] = __builtin_amdgcn_mfma_f32_16x16x32_f16(af3, bf, acc[3][n],0,0,0);
            }
            __syncthreads();   // all reads of Wb[cur] done; next-slab copies landed
        }

        // ================= epilogue for task s =================
        const float* bias =
            s==0 ? bu  + u*DD :
            s==1 ? bsx + u*DD :
            s==2 ? bsy + u*DD :
            s==3 ? bpx + (u*NU+j0)*DD :
            s==4 ? bpx + (u*NU+j1)*DD :
            s==5 ? bpy + (j0*NU+u)*DD :
                   bpy + (j1*NU+u)*DD;
        float bv[4];
        #pragma unroll
        for (int n = 0; n < 4; ++n) bv[n] = bias[wq*64 + n*16 + l15];
        #pragma unroll
        for (int m = 0; m < 4; ++m)
            #pragma unroll
            for (int n = 0; n < 4; ++n)
                #pragma unroll
                for (int r = 0; r < 4; ++r) acc[m][n][r] += bv[n];

        if (s == 0) {
            float wrv[4];
            #pragma unroll
            for (int n = 0; n < 4; ++n) wrv[n] = wr[u*DD + wq*64 + n*16 + l15];
            float pm[4][4];
            #pragma unroll
            for (int m = 0; m < 4; ++m)
                #pragma unroll
                for (int r = 0; r < 4; ++r) {
                    float t = 0.f;
                    #pragma unroll
                    for (int n = 0; n < 4; ++n) t = fmaf(fmaxf(acc[m][n][r], 0.f), wrv[n], t);
                    pm[m][r] = t;
                }
            #pragma unroll
            for (int mask = 1; mask <= 8; mask <<= 1)
                #pragma unroll
                for (int m = 0; m < 4; ++m)
                    #pragma unroll
                    for (int r = 0; r < 4; ++r) pm[m][r] += __shfl_xor(pm[m][r], mask);
            if (l15 == 0) {
                #pragma unroll
                for (int m = 0; m < 4; ++m)
                    #pragma unroll
                    for (int r = 0; r < 4; ++r) ep_sum[wq][m*16 + lg*4 + r] = pm[m][r];
            }
            __syncthreads();
            if (tid < 64)
                ws[OFF_UNARY + (size_t)u*MM + row0 + tid] =
                    ep_sum[0][tid]+ep_sum[1][tid]+ep_sum[2][tid]+ep_sum[3][tid] + br[u];
        } else {
            float pm[4][4];
            #pragma unroll
            for (int m = 0; m < 4; ++m)
                #pragma unroll
                for (int r = 0; r < 4; ++r) {
                    float t = 0.f;
                    #pragma unroll
                    for (int n = 0; n < 4; ++n) t = fmaf(acc[m][n][r], acc[m][n][r], t);
                    pm[m][r] = t;
                }
            #pragma unroll
            for (int mask = 1; mask <= 8; mask <<= 1)
                #pragma unroll
                for (int m = 0; m < 4; ++m)
                    #pragma unroll
                    for (int r = 0; r < 4; ++r) pm[m][r] += __shfl_xor(pm[m][r], mask);
            if (l15 == 0) {
                #pragma unroll
                for (int m = 0; m < 4; ++m)
                    #pragma unroll
                    for (int r = 0; r < 4; ++r) ep_sum[wq][m*16 + lg*4 + r] = pm[m][r];
            }
            __syncthreads();
            if (tid < 64) {
                const float ssum = ep_sum[0][tid]+ep_sum[1][tid]+ep_sum[2][tid]+ep_sum[3][tid];
                const float inv = 1.f / fmaxf(sqrtf(ssum), 1e-12f);
                ep_inv[tid] = inv;
                if (s == 1)      ws[OFF_INVXS + (size_t)u  *MM + row0 + tid] = inv;
                else if (s == 3) ws[OFF_INVXP + (size_t)px0*MM + row0 + tid] = inv;
                else if (s == 4) ws[OFF_INVXP + (size_t)px1*MM + row0 + tid] = inv;
                else if (s == 5) ws[OFF_INVYP + (size_t)py0*MM + row0 + tid] = inv;
                else if (s == 6) ws[OFF_INVYP + (size_t)py1*MM + row0 + tid] = inv;
            }
            __syncthreads();
            if (s >= 2) {
                float invv[4][4];
                #pragma unroll
                for (int m = 0; m < 4; ++m)
                    #pragma unroll
                    for (int r = 0; r < 4; ++r) invv[m][r] = ep_inv[m*16 + lg*4 + r];
                float qn[4];
                #pragma unroll
                for (int n = 0; n < 4; ++n) {
                    float t = 0.f;
                    #pragma unroll
                    for (int m = 0; m < 4; ++m)
                        #pragma unroll
                        for (int r = 0; r < 4; ++r) t = fmaf(acc[m][n][r], invv[m][r], t);
                    qn[n] = t;
                }
                #pragma unroll
                for (int n = 0; n < 4; ++n) {
                    qn[n] += __shfl_xor(qn[n], 16);
                    qn[n] += __shfl_xor(qn[n], 32);
                }
                float* bar =
                    s==2 ? ws + OFF_YBAR  + ((size_t)u  *BB + b)*DD :
                    s==3 ? ws + OFF_XPBAR + ((size_t)px0*BB + b)*DD :
                    s==4 ? ws + OFF_XPBAR + ((size_t)px1*BB + b)*DD :
                    s==5 ? ws + OFF_YPBAR + ((size_t)py0*BB + b)*DD :
                           ws + OFF_YPBAR + ((size_t)py1*BB + b)*DD;
                if (lane < 16) {
                    #pragma unroll
                    for (int n = 0; n < 4; ++n)
                        atomicAdd(&bar[wq*64 + n*16 + lane], qn[n]);
                }
            }
        }
        #pragma unroll
        for (int m = 0; m < 4; ++m)
            #pragma unroll
            for (int n = 0; n < 4; ++n) acc[m][n] = (f32x4)0.f;
        __syncthreads();   // protect ep_sum/ep_inv reuse next task
    }
#undef STAGE
}

// ---------------------------------------------------------------------------
// Pass 2a: proj[d] = sum_e W[e][d] * (bar[e]/N);  cs = sum_e bias[e]*(bar[e]/N)
// ---------------------------------------------------------------------------
__global__ __launch_bounds__(256) void proj_kernel(
    const float* __restrict__ Wsx, const float* __restrict__ bsx,
    const float* __restrict__ Wpx, const float* __restrict__ bpx,
    const float* __restrict__ Wpy, const float* __restrict__ bpy,
    float* __restrict__ ws)
{
    __shared__ float barl[DD];
    __shared__ float redl[256];
    const int task = blockIdx.x >> 4;
    const int b    = blockIdx.x & 15;
    const int tid  = threadIdx.x;
    const float *W, *bias, *barp;
    float *projp, *csp;
    if (task < 3) {
        const int uu = task;
        W = Wsx + (size_t)uu*DD*DD; bias = bsx + uu*DD;
        barp  = ws + OFF_YBAR  + ((size_t)uu*BB + b)*DD;
        projp = ws + OFF_PROJS + ((size_t)uu*BB + b)*DD;
        csp   = ws + OFF_CSS + uu*BB + b;
    } else if (task < 9) {
        const int p = task - 3; const int i = p>>1;
        const int j = (p&1) == 0 ? (i==0?1:0) : (i==2?1:2);
        W = Wpx + (size_t)(i*NU+j)*DD*DD; bias = bpx + (i*NU+j)*DD;
        barp  = ws + OFF_YPBAR + ((size_t)p*BB + b)*DD;
        projp = ws + OFF_PROJX + ((size_t)p*BB + b)*DD;
        csp   = ws + OFF_CSX + p*BB + b;
    } else {
        const int p = task - 9; const int i = p>>1;
        const int j = (p&1) == 0 ? (i==0?1:0) : (i==2?1:2);
        W = Wpy + (size_t)(i*NU+j)*DD*DD; bias = bpy + (i*NU+j)*DD;
        barp  = ws + OFF_XPBAR + ((size_t)p*BB + b)*DD;
        projp = ws + OFF_PROJY + ((size_t)p*BB + b)*DD;
        csp   = ws + OFF_CSY + p*BB + b;
    }
    barl[tid] = barp[tid] * (1.f / NN);
    __syncthreads();
    float s = 0.f;
    for (int e = 0; e < DD; ++e) s = fmaf(W[(size_t)e*DD + tid], barl[e], s);
    projp[tid] = s;
    redl[tid] = bias[tid] * barl[tid];
    __syncthreads();
    for (int st = 128; st > 0; st >>= 1) {
        if (tid < st) redl[tid] += redl[tid + st];
        __syncthreads();
    }
    if (tid == 0) *csp = redl[0];
}

// ---------------------------------------------------------------------------
// Pass 2b (util-fused): per 32-token tile of util u, dot U rows against the
// 5 proj vectors that have u as source; write 5 potential arrays.
// ---------------------------------------------------------------------------
__global__ __launch_bounds__(256) void pots_kernel(
    const float* __restrict__ u0, const float* __restrict__ u1, const float* __restrict__ u2,
    float* __restrict__ ws)
{
    __shared__ float projl[5][DD];
    __shared__ float csl[5];
    const int u    = blockIdx.y;
    const int row0 = blockIdx.x * 32;
    const int b    = row0 >> 10;
    const int tid  = threadIdx.x;
    const int px0 = u*2, px1 = u*2+1;
    const int py0 = (u==0)?2:((u==1)?0:1);
    const int py1 = (u==0)?4:((u==1)?5:3);

    projl[0][tid] = ws[OFF_PROJS + ((size_t)u  *BB + b)*DD + tid];
    projl[1][tid] = ws[OFF_PROJX + ((size_t)px0*BB + b)*DD + tid];
    projl[2][tid] = ws[OFF_PROJX + ((size_t)px1*BB + b)*DD + tid];
    projl[3][tid] = ws[OFF_PROJY + ((size_t)py0*BB + b)*DD + tid];
    projl[4][tid] = ws[OFF_PROJY + ((size_t)py1*BB + b)*DD + tid];
    if (tid == 0) {
        csl[0] = ws[OFF_CSS + u*BB + b];
        csl[1] = ws[OFF_CSX + px0*BB + b];
        csl[2] = ws[OFF_CSX + px1*BB + b];
        csl[3] = ws[OFF_CSY + py0*BB + b];
        csl[4] = ws[OFF_CSY + py1*BB + b];
    }
    __syncthreads();
    const float* src = selU(u,u0,u1,u2);
    const int token = tid >> 3, q = tid & 7;
    const int row = row0 + token;
    float a0=0.f,a1=0.f,a2=0.f,a3=0.f,a4=0.f;
    #pragma unroll
    for (int cc = 0; cc < 8; ++cc) {
        const int d0 = q*32 + cc*4;
        const float4 v  = *reinterpret_cast<const float4*>(src + (size_t)row*DD + d0);
        const float4 p0 = *reinterpret_cast<const float4*>(&projl[0][d0]);
        const float4 p1 = *reinterpret_cast<const float4*>(&projl[1][d0]);
        const float4 p2 = *reinterpret_cast<const float4*>(&projl[2][d0]);
        const float4 p3 = *reinterpret_cast<const float4*>(&projl[3][d0]);
        const float4 p4 = *reinterpret_cast<const float4*>(&projl[4][d0]);
        a0 = fmaf(v.x,p0.x,fmaf(v.y,p0.y,fmaf(v.z,p0.z,fmaf(v.w,p0.w,a0))));
        a1 = fmaf(v.x,p1.x,fmaf(v.y,p1.y,fmaf(v.z,p1.z,fmaf(v.w,p1.w,a1))));
        a2 = fmaf(v.x,p2.x,fmaf(v.y,p2.y,fmaf(v.z,p2.z,fmaf(v.w,p2.w,a2))));
        a3 = fmaf(v.x,p3.x,fmaf(v.y,p3.y,fmaf(v.z,p3.z,fmaf(v.w,p3.w,a3))));
        a4 = fmaf(v.x,p4.x,fmaf(v.y,p4.y,fmaf(v.z,p4.z,fmaf(v.w,p4.w,a4))));
    }
    #pragma unroll
    for (int mask = 1; mask <= 4; mask <<= 1) {
        a0 += __shfl_xor(a0, mask, 8);
        a1 += __shfl_xor(a1, mask, 8);
        a2 += __shfl_xor(a2, mask, 8);
        a3 += __shfl_xor(a3, mask, 8);
        a4 += __shfl_xor(a4, mask, 8);
    }
    if (q == 0) {
        ws[OFF_SELFP + (size_t)u  *MM + row] = (a0 + csl[0]) * ws[OFF_INVXS + (size_t)u  *MM + row];
        ws[OFF_POTX  + (size_t)px0*MM + row] = (a1 + csl[1]) * ws[OFF_INVXP + (size_t)px0*MM + row];
        ws[OFF_POTX  + (size_t)px1*MM + row] = (a2 + csl[2]) * ws[OFF_INVXP + (size_t)px1*MM + row];
        ws[OFF_POTY  + (size_t)py0*MM + row] = (a3 + csl[3]) * ws[OFF_INVYP + (size_t)py0*MM + row];
        ws[OFF_POTY  + (size_t)py1*MM + row] = (a4 + csl[4]) * ws[OFF_INVYP + (size_t)py1*MM + row];
    }
}

// ---------------------------------------------------------------------------
// Pass 3a: per (j,b): logits for i=0..2 -> softmax -> normalized probs to ws
// ---------------------------------------------------------------------------
__global__ __launch_bounds__(256) void attend_logits_kernel(
    const float* __restrict__ wdiag, const float* __restrict__ wpair,
    float* __restrict__ ws)
{
    __shared__ float el[3][NN];
    __shared__ float redl[256];
    const int c = blockIdx.x;          // 0..47
    const int j = c >> 4, b = c & 15;
    const int tid = threadIdx.x;

    #pragma unroll
    for (int i = 0; i < 3; ++i) {
        if (i == j) {
            const int p1 = i*2, p2 = i*2+1;
            const float w0 = wdiag[i*4+0], w1 = wdiag[i*4+1], w2 = wdiag[i*4+2], w3 = wdiag[i*4+3];
            for (int n = tid; n < NN; n += 256) {
                const int row = b*NN + n;
                el[i][n] = w0*ws[OFF_UNARY + i*MM + row] + w1*ws[OFF_SELFP + i*MM + row]
                         + w2*ws[OFF_POTX + p1*MM + row] + w3*ws[OFF_POTX + p2*MM + row];
            }
        } else {
            const int p = i*2 + (j > i ? j-1 : j);
            const float w0 = wpair[(i*3+j)*3+0], w1 = wpair[(i*3+j)*3+1], w2 = wpair[(i*3+j)*3+2];
            for (int n = tid; n < NN; n += 256) {
                const int row = b*NN + n;
                el[i][n] = w0*ws[OFF_UNARY + j*MM + row] + w1*ws[OFF_SELFP + j*MM + row]
                         + w2*ws[OFF_POTY + p*MM + row];
            }
        }
    }
    __syncthreads();
    #pragma unroll
    for (int i = 0; i < 3; ++i) {
        float m = -1e30f;
        for (int n = tid; n < NN; n += 256) m = fmaxf(m, el[i][n]);
        redl[tid] = m; __syncthreads();
        for (int st = 128; st > 0; st >>= 1) {
            if (tid < st) redl[tid] = fmaxf(redl[tid], redl[tid+st]);
            __syncthreads();
        }
        m = redl[0];
        __syncthreads();
        float ss = 0.f;
        for (int n = tid; n < NN; n += 256) {
            const float e = expf(el[i][n] - m);
            el[i][n] = e;
            ss += e;
        }
        redl[tid] = ss; __syncthreads();
        for (int st = 128; st > 0; st >>= 1) {
            if (tid < st) redl[tid] += redl[tid+st];
            __syncthreads();
        }
        const float invS = 1.f / redl[0];
        __syncthreads();
        for (int n = tid; n < NN; n += 256)
            ws[OFF_PROB + ((size_t)(i*3+j)*BB + b)*NN + n] = el[i][n] * invS;
    }
}

// ---------------------------------------------------------------------------
// Pass 3b: chunked weighted sum: partial[(i,j,b)][chunk][d]
// ---------------------------------------------------------------------------
__global__ __launch_bounds__(256) void attend_sum_kernel(
    const float* __restrict__ u0, const float* __restrict__ u1, const float* __restrict__ u2,
    const float* __restrict__ ws, float* __restrict__ wso)
{
    __shared__ float pl[3][128];
    const int x  = blockIdx.x;         // 0..383
    const int jb = x >> 3, ch = x & 7;
    const int j = jb >> 4, b = jb & 15;
    const int tid = threadIdx.x;

    for (int t = tid; t < 384; t += 256) {
        const int i = t >> 7, n = t & 127;
        pl[i][n] = ws[OFF_PROB + ((size_t)(i*3+j)*BB + b)*NN + ch*128 + n];
    }
    __syncthreads();
    const float* Uj = selU(j, u0, u1, u2) + ((size_t)b*NN + ch*128)*DD;
    float a0 = 0.f, a1 = 0.f, a2 = 0.f;
    #pragma unroll 4
    for (int n = 0; n < 128; ++n) {
        const float v = Uj[(size_t)n*DD + tid];
        a0 = fmaf(pl[0][n], v, a0);
        a1 = fmaf(pl[1][n], v, a1);
        a2 = fmaf(pl[2][n], v, a2);
    }
    wso[OFF_PART + (((size_t)(0*3+j)*BB + b)*8 + ch)*DD + tid] = a0;
    wso[OFF_PART + (((size_t)(1*3+j)*BB + b)*8 + ch)*DD + tid] = a1;
    wso[OFF_PART + (((size_t)(2*3+j)*BB + b)*8 + ch)*DD + tid] = a2;
}

// ---------------------------------------------------------------------------
// Pass 3c: reduce chunks -> out
// ---------------------------------------------------------------------------
__global__ __launch_bounds__(256) void attend_reduce_kernel(
    const float* __restrict__ ws, float* __restrict__ out)
{
    const int ijb = blockIdx.x;        // 0..143
    const int tid = threadIdx.x;
    float s = 0.f;
    #pragma unroll
    for (int ch = 0; ch < 8; ++ch)
        s += ws[OFF_PART + ((size_t)ijb*8 + ch)*DD + tid];
    out[(size_t)ijb*DD + tid] = s;
}

// ---------------------------------------------------------------------------
extern "C" void kernel_launch(void* const* d_in, const int* in_sizes, int n_in,
                              void* d_out, int out_size, void* d_ws, size_t ws_size,
                              hipStream_t stream)
{
    (void)in_sizes; (void)n_in; (void)out_size; (void)ws_size;
    const float* u0    = (const float*)d_in[0];
    const float* u1    = (const float*)d_in[1];
    const float* u2    = (const float*)d_in[2];
    const float* Wu    = (const float*)d_in[3];
    const float* bu    = (const float*)d_in[4];
    const float* wr    = (const float*)d_in[5];
    const float* br    = (const float*)d_in[6];
    const float* Wsx   = (const float*)d_in[7];
    const float* bsx   = (const float*)d_in[8];
    const float* Wsy   = (const float*)d_in[9];
    const float* bsy   = (const float*)d_in[10];
    const float* Wpx   = (const float*)d_in[11];
    const float* bpx   = (const float*)d_in[12];
    const float* Wpy   = (const float*)d_in[13];
    const float* bpy   = (const float*)d_in[14];
    const float* wdiag = (const float*)d_in[15];
    const float* wpair = (const float*)d_in[16];
    float* ws  = (float*)d_ws;
    float* out = (float*)d_out;

    // zero the atomic accumulators (Ybar, Xpbar, Ypbar are contiguous)
    hipMemsetAsync(ws + OFF_YBAR, 0, (size_t)(NU + 2*NPAIR)*BB*DD*sizeof(float), stream);

    dim3 gw(21, 8);
    convw_kernel<<<gw, 256, 0, stream>>>(Wu, Wsx, Wsy, Wpx, Wpy, ws);

    dim3 g1(MM/64, 3);
    pass1_kernel<<<g1, 256, 0, stream>>>(u0,u1,u2,bu,wr,br,bsx,bsy,bpx,bpy,ws);

    proj_kernel<<<15*BB, 256, 0, stream>>>(Wsx,bsx,Wpx,bpx,Wpy,bpy,ws);
    dim3 g2(MM/32, 3);
    pots_kernel<<<g2, 256, 0, stream>>>(u0,u1,u2,ws);

    attend_logits_kernel<<<3*BB, 256, 0, stream>>>(wdiag, wpair, ws);
    attend_sum_kernel<<<3*BB*8, 256, 0, stream>>>(u0,u1,u2, ws, ws);
    attend_reduce_kernel<<<9*BB, 256, 0, stream>>>(ws, out);
}

// Round 13
// 126.403 us; speedup vs baseline: 2.0657x; 1.2222x over previous
//
#include <hip/hip_runtime.h>
#include <math.h>

#define NU 3
#define BB 16
#define NN 1024
#define DD 256
#define MM (BB*NN)      // 16384 tokens per util
#define NPAIR 6

// workspace layout (float element offsets)
#define OFF_UNARY  0
#define OFF_INVXS  (OFF_UNARY + NU*MM)
#define OFF_INVXP  (OFF_INVXS + NU*MM)
#define OFF_INVYP  (OFF_INVXP + NPAIR*MM)
#define OFF_YBAR   (OFF_INVYP + NPAIR*MM)          // bars contiguous for one memset
#define OFF_XPBAR  (OFF_YBAR + NU*BB*DD)
#define OFF_YPBAR  (OFF_XPBAR + NPAIR*BB*DD)
#define OFF_PROJS  (OFF_YPBAR + NPAIR*BB*DD)
#define OFF_PROJX  (OFF_PROJS + NU*BB*DD)
#define OFF_PROJY  (OFF_PROJX + NPAIR*BB*DD)
#define OFF_CSS    (OFF_PROJY + NPAIR*BB*DD)
#define OFF_CSX    (OFF_CSS + NU*BB)
#define OFF_CSY    (OFF_CSX + NPAIR*BB)
#define OFF_SELFP  (OFF_CSY + NPAIR*BB)
#define OFF_POTX   (OFF_SELFP + NU*MM)
#define OFF_POTY   (OFF_POTX + NPAIR*MM)
#define WS_FLOATS  (OFF_POTY + NPAIR*MM)           // = 663792
// f16 weights, fragment order: 21 slots x 65536 halves = 688128 floats
#define OFF_PROB   (WS_FLOATS + 21*32768)
#define OFF_PART   (OFF_PROB + 9*BB*NN)
// end = OFF_PART + 9*BB*8*DD  (~7.2 MB total)

typedef _Float16 half8 __attribute__((ext_vector_type(8)));
typedef float f32x4 __attribute__((ext_vector_type(4)));

__device__ __forceinline__ const float* selU(int u, const float* u0, const float* u1, const float* u2) {
    return u == 0 ? u0 : (u == 1 ? u1 : u2);
}
__device__ __forceinline__ half8 cvt8(float4 a, float4 b) {
    half8 h = { (_Float16)a.x,(_Float16)a.y,(_Float16)a.z,(_Float16)a.w,
                (_Float16)b.x,(_Float16)b.y,(_Float16)b.z,(_Float16)b.w };
    return h;
}

// ---------------------------------------------------------------------------
// Weight convert: fp32 -> f16, fragment order. Slot (u, s=0..6):
// s0 Wu[u]; s1 Wsx[u]; s2 Wsy[u]; s3/s4 Wpx[u->j0/j1]; s5/s6 Wpy[j0/j1->u].
// Per slot, half index = ((et*8 + kc)*64 + lane)*8 + h, where
// e = et*16 + (lane&15), k = kc*32 + (lane>>4)*8 + h. A wave's bf fragment
// load is then 1KB contiguous.
// ---------------------------------------------------------------------------
__global__ __launch_bounds__(256) void convw_kernel(
    const float* __restrict__ Wu, const float* __restrict__ Wsx, const float* __restrict__ Wsy,
    const float* __restrict__ Wpx, const float* __restrict__ Wpy, float* __restrict__ ws)
{
    const int slot = blockIdx.x;          // 0..20
    const int kc   = blockIdx.y;          // 0..7
    const int tid  = threadIdx.x;
    const int u = slot / 7, s = slot % 7;
    const int j0 = (u==0)?1:0, j1 = (u==2)?1:2;
    const float* W =
        s==0 ? Wu  + (size_t)u*DD*DD :
        s==1 ? Wsx + (size_t)u*DD*DD :
        s==2 ? Wsy + (size_t)u*DD*DD :
        s==3 ? Wpx + (size_t)(u*NU+j0)*DD*DD :
        s==4 ? Wpx + (size_t)(u*NU+j1)*DD*DD :
        s==5 ? Wpy + (size_t)(j0*NU+u)*DD*DD :
               Wpy + (size_t)(j1*NU+u)*DD*DD;
    _Float16* wh = (_Float16*)(ws + WS_FLOATS) + (size_t)slot*65536;
    #pragma unroll
    for (int g = 0; g < 4; ++g) {
        const int idx16 = g*256 + tid;        // 0..1023 = et*64 + lane
        const int et   = idx16 >> 6;
        const int lane = idx16 & 63;
        const int e  = et*16 + (lane & 15);
        const int k0 = kc*32 + (lane >> 4)*8;
        const float* sp = W + (size_t)e*DD + k0;
        const float4 v0 = *reinterpret_cast<const float4*>(sp);
        const float4 v1 = *reinterpret_cast<const float4*>(sp + 4);
        *reinterpret_cast<half8*>(wh + ((size_t)(et*8 + kc)*64 + lane)*8) = cvt8(v0, v1);
    }
}

// ---------------------------------------------------------------------------
// Pass 1: grid (MM/128, 3). Block = 128-token tile of util u, 4 waves; wave
// wq owns e in [wq*64, wq*64+64) x ALL 128 tokens (acc[8][4]). U tile f16 LDS
// (XOR-swizzled), all A-fragments read from LDS per slab; W streamed
// global->register dist-1. TASK ORDER ROTATED PER BLOCK (s = (si+rot)%7):
// concurrent blocks walk DIFFERENT weight regions, de-correlating the L2/L3
// same-line request storm that every prior (in-phase) structure exhibited.
// K-loop barrier-free; 7 tasks, fused epilogues.
// ---------------------------------------------------------------------------
__global__ __launch_bounds__(256, 2) void pass1_kernel(
    const float* __restrict__ u0, const float* __restrict__ u1, const float* __restrict__ u2,
    const float* __restrict__ bu, const float* __restrict__ wr, const float* __restrict__ br,
    const float* __restrict__ bsx, const float* __restrict__ bsy,
    const float* __restrict__ bpx, const float* __restrict__ bpy,
    float* __restrict__ ws)
{
    __shared__ __align__(16) _Float16 Ub[32768];   // [kc=8][tok=128][32k] swizzled
    __shared__ float ep_sum[4][128];
    __shared__ float ep_inv[128];

    const int tid  = threadIdx.x;
    const int u    = blockIdx.y;
    const int row0 = blockIdx.x * 128;
    const int b    = row0 >> 10;

    const int j0 = (u==0)?1:0, j1 = (u==2)?1:2;
    const int px0 = u*2, px1 = u*2+1;
    const int py0 = (u==0)?2:((u==1)?0:1);
    const int py1 = (u==0)?4:((u==1)?5:3);

    const float* src = selU(u,u0,u1,u2);
    const _Float16* whU = (const _Float16*)(ws + WS_FLOATS) + (size_t)u*7*65536;

    const int lane = tid & 63, wq = tid >> 6;
    const int l15 = lane & 15, lg = lane >> 4;
    const int swz = (l15 >> 1) & 3;
    const int kxor = (lg ^ swz) * 8;

    // per-wave W base: fragment (n,kc) at wbase + s*65536 + n*4096 + kc*512
    const _Float16* wbase = whU + (size_t)wq*16384 + (size_t)lane*8;

    // task-order rotation: de-phase concurrent blocks' weight streams
    const int rot = blockIdx.x % 7;

    f32x4 acc[8][4];
    #pragma unroll
    for (int m = 0; m < 8; ++m)
        #pragma unroll
        for (int n = 0; n < 4; ++n) acc[m][n] = (f32x4)0.f;

    half8 bfA[4], bfB[4];

#define BFLD(DST, S, KC) { \
    _Pragma("unroll") \
    for (int n_ = 0; n_ < 4; ++n_) \
        DST[n_] = *reinterpret_cast<const half8*>(wbase + (size_t)(S)*65536 + n_*4096 + (KC)*512); }

#define SLAB(KC, BFC, BFN, PRED, SPF, KPF) { \
    if (PRED) { BFLD(BFN, SPF, KPF) } \
    half8 afd[8]; \
    _Pragma("unroll") \
    for (int m_ = 0; m_ < 8; ++m_) \
        afd[m_] = *reinterpret_cast<const half8*>(&Ub[(KC)*4096 + (m_*16 + l15)*32 + kxor]); \
    _Pragma("unroll") \
    for (int n_ = 0; n_ < 4; ++n_) \
        _Pragma("unroll") \
        for (int m_ = 0; m_ < 8; ++m_) \
            acc[m_][n_] = __builtin_amdgcn_mfma_f32_16x16x32_f16(afd[m_], BFC[n_], acc[m_][n_],0,0,0); }

    // issue first W fragment loads early (hide under U staging)
    BFLD(bfA, rot, 0)

    // U prologue: 128 tok x 256 k fp32 -> f16 swizzled LDS (once per block)
    #pragma unroll
    for (int c = 0; c < 16; ++c) {
        const int G2 = c*256 + tid;          // 0..4095
        const int t  = G2 >> 5;              // token 0..127
        const int gk = G2 & 31;              // k-granule 0..31
        const int kc = gk >> 2, kg = gk & 3;
        const float* p = src + (size_t)(row0 + t)*DD + gk*8;
        const float4 v0 = *reinterpret_cast<const float4*>(p);
        const float4 v1 = *reinterpret_cast<const float4*>(p + 4);
        const int kgs = kg ^ ((t >> 1) & 3);
        *reinterpret_cast<half8*>(&Ub[kc*4096 + t*32 + kgs*8]) = cvt8(v0, v1);
    }
    __syncthreads();

    for (int si = 0; si < 7; ++si) {
        const int s     = (si + rot) % 7;
        const int snext = (s + 1) % 7;
        SLAB(0, bfA, bfB, 1,        s,     1)
        SLAB(1, bfB, bfA, 1,        s,     2)
        SLAB(2, bfA, bfB, 1,        s,     3)
        SLAB(3, bfB, bfA, 1,        s,     4)
        SLAB(4, bfA, bfB, 1,        s,     5)
        SLAB(5, bfB, bfA, 1,        s,     6)
        SLAB(6, bfA, bfB, 1,        s,     7)
        SLAB(7, bfB, bfA, (si < 6), snext, 0)

        // ================= epilogue for task s =================
        const float* bias =
            s==0 ? bu  + u*DD :
            s==1 ? bsx + u*DD :
            s==2 ? bsy + u*DD :
            s==3 ? bpx + (u*NU+j0)*DD :
            s==4 ? bpx + (u*NU+j1)*DD :
            s==5 ? bpy + (j0*NU+u)*DD :
                   bpy + (j1*NU+u)*DD;
        float bv[4];
        #pragma unroll
        for (int n = 0; n < 4; ++n) bv[n] = bias[wq*64 + n*16 + l15];
        #pragma unroll
        for (int m = 0; m < 8; ++m)
            #pragma unroll
            for (int n = 0; n < 4; ++n)
                #pragma unroll
                for (int r = 0; r < 4; ++r) acc[m][n][r] += bv[n];

        if (s == 0) {
            float wrv[4];
            #pragma unroll
            for (int n = 0; n < 4; ++n) wrv[n] = wr[u*DD + wq*64 + n*16 + l15];
            float pm[8][4];
            #pragma unroll
            for (int m = 0; m < 8; ++m)
                #pragma unroll
                for (int r = 0; r < 4; ++r) {
                    float t = 0.f;
                    #pragma unroll
                    for (int n = 0; n < 4; ++n) t = fmaf(fmaxf(acc[m][n][r], 0.f), wrv[n], t);
                    pm[m][r] = t;
                }
            #pragma unroll
            for (int mask = 1; mask <= 8; mask <<= 1)
                #pragma unroll
                for (int m = 0; m < 8; ++m)
                    #pragma unroll
                    for (int r = 0; r < 4; ++r) pm[m][r] += __shfl_xor(pm[m][r], mask);
            if (l15 == 0) {
                #pragma unroll
                for (int m = 0; m < 8; ++m)
                    #pragma unroll
                    for (int r = 0; r < 4; ++r) ep_sum[wq][m*16 + lg*4 + r] = pm[m][r];
            }
            __syncthreads();
            if (tid < 128)
                ws[OFF_UNARY + (size_t)u*MM + row0 + tid] =
                    ep_sum[0][tid]+ep_sum[1][tid]+ep_sum[2][tid]+ep_sum[3][tid] + br[u];
        } else {
            float pm[8][4];
            #pragma unroll
            for (int m = 0; m < 8; ++m)
                #pragma unroll
                for (int r = 0; r < 4; ++r) {
                    float t = 0.f;
                    #pragma unroll
                    for (int n = 0; n < 4; ++n) t = fmaf(acc[m][n][r], acc[m][n][r], t);
                    pm[m][r] = t;
                }
            #pragma unroll
            for (int mask = 1; mask <= 8; mask <<= 1)
                #pragma unroll
                for (int m = 0; m < 8; ++m)
                    #pragma unroll
                    for (int r = 0; r < 4; ++r) pm[m][r] += __shfl_xor(pm[m][r], mask);
            if (l15 == 0) {
                #pragma unroll
                for (int m = 0; m < 8; ++m)
                    #pragma unroll
                    for (int r = 0; r < 4; ++r) ep_sum[wq][m*16 + lg*4 + r] = pm[m][r];
            }
            __syncthreads();
            if (tid < 128) {
                const float ssum = ep_sum[0][tid]+ep_sum[1][tid]+ep_sum[2][tid]+ep_sum[3][tid];
                const float inv = 1.f / fmaxf(sqrtf(ssum), 1e-12f);
                ep_inv[tid] = inv;
                if (s == 1)      ws[OFF_INVXS + (size_t)u  *MM + row0 + tid] = inv;
                else if (s == 3) ws[OFF_INVXP + (size_t)px0*MM + row0 + tid] = inv;
                else if (s == 4) ws[OFF_INVXP + (size_t)px1*MM + row0 + tid] = inv;
                else if (s == 5) ws[OFF_INVYP + (size_t)py0*MM + row0 + tid] = inv;
                else if (s == 6) ws[OFF_INVYP + (size_t)py1*MM + row0 + tid] = inv;
            }
            __syncthreads();
            if (s >= 2) {
                float qn[4];
                #pragma unroll
                for (int n = 0; n < 4; ++n) qn[n] = 0.f;
                #pragma unroll
                for (int m = 0; m < 8; ++m) {
                    float invv[4];
                    #pragma unroll
                    for (int r = 0; r < 4; ++r) invv[r] = ep_inv[m*16 + lg*4 + r];
                    #pragma unroll
                    for (int n = 0; n < 4; ++n)
                        #pragma unroll
                        for (int r = 0; r < 4; ++r) qn[n] = fmaf(acc[m][n][r], invv[r], qn[n]);
                }
                #pragma unroll
                for (int n = 0; n < 4; ++n) {
                    qn[n] += __shfl_xor(qn[n], 16);
                    qn[n] += __shfl_xor(qn[n], 32);
                }
                float* bar =
                    s==2 ? ws + OFF_YBAR  + ((size_t)u  *BB + b)*DD :
                    s==3 ? ws + OFF_XPBAR + ((size_t)px0*BB + b)*DD :
                    s==4 ? ws + OFF_XPBAR + ((size_t)px1*BB + b)*DD :
                    s==5 ? ws + OFF_YPBAR + ((size_t)py0*BB + b)*DD :
                           ws + OFF_YPBAR + ((size_t)py1*BB + b)*DD;
                if (lane < 16) {
                    #pragma unroll
                    for (int n = 0; n < 4; ++n)
                        atomicAdd(&bar[wq*64 + n*16 + lane], qn[n]);
                }
            }
        }
        #pragma unroll
        for (int m = 0; m < 8; ++m)
            #pragma unroll
            for (int n = 0; n < 4; ++n) acc[m][n] = (f32x4)0.f;
        __syncthreads();   // protect ep_sum/ep_inv reuse next task
    }
#undef BFLD
#undef SLAB
}

// ---------------------------------------------------------------------------
// Pass 2a: proj[d] = sum_e W[e][d] * (bar[e]/N);  cs = sum_e bias[e]*(bar[e]/N)
// ---------------------------------------------------------------------------
__global__ __launch_bounds__(256) void proj_kernel(
    const float* __restrict__ Wsx, const float* __restrict__ bsx,
    const float* __restrict__ Wpx, const float* __restrict__ bpx,
    const float* __restrict__ Wpy, const float* __restrict__ bpy,
    float* __restrict__ ws)
{
    __shared__ float barl[DD];
    __shared__ float redl[256];
    const int task = blockIdx.x >> 4;
    const int b    = blockIdx.x & 15;
    const int tid  = threadIdx.x;
    const float *W, *bias, *barp;
    float *projp, *csp;
    if (task < 3) {
        const int uu = task;
        W = Wsx + (size_t)uu*DD*DD; bias = bsx + uu*DD;
        barp  = ws + OFF_YBAR  + ((size_t)uu*BB + b)*DD;
        projp = ws + OFF_PROJS + ((size_t)uu*BB + b)*DD;
        csp   = ws + OFF_CSS + uu*BB + b;
    } else if (task < 9) {
        const int p = task - 3; const int i = p>>1;
        const int j = (p&1) == 0 ? (i==0?1:0) : (i==2?1:2);
        W = Wpx + (size_t)(i*NU+j)*DD*DD; bias = bpx + (i*NU+j)*DD;
        barp  = ws + OFF_YPBAR + ((size_t)p*BB + b)*DD;
        projp = ws + OFF_PROJX + ((size_t)p*BB + b)*DD;
        csp   = ws + OFF_CSX + p*BB + b;
    } else {
        const int p = task - 9; const int i = p>>1;
        const int j = (p&1) == 0 ? (i==0?1:0) : (i==2?1:2);
        W = Wpy + (size_t)(i*NU+j)*DD*DD; bias = bpy + (i*NU+j)*DD;
        barp  = ws + OFF_XPBAR + ((size_t)p*BB + b)*DD;
        projp = ws + OFF_PROJY + ((size_t)p*BB + b)*DD;
        csp   = ws + OFF_CSY + p*BB + b;
    }
    barl[tid] = barp[tid] * (1.f / NN);
    __syncthreads();
    float s = 0.f;
    for (int e = 0; e < DD; ++e) s = fmaf(W[(size_t)e*DD + tid], barl[e], s);
    projp[tid] = s;
    redl[tid] = bias[tid] * barl[tid];
    __syncthreads();
    for (int st = 128; st > 0; st >>= 1) {
        if (tid < st) redl[tid] += redl[tid + st];
        __syncthreads();
    }
    if (tid == 0) *csp = redl[0];
}

// ---------------------------------------------------------------------------
// Pass 2b (util-fused): per 32-token tile of util u, dot U rows against the
// 5 proj vectors that have u as source; write 5 potential arrays.
// ---------------------------------------------------------------------------
__global__ __launch_bounds__(256) void pots_kernel(
    const float* __restrict__ u0, const float* __restrict__ u1, const float* __restrict__ u2,
    float* __restrict__ ws)
{
    __shared__ float projl[5][DD];
    __shared__ float csl[5];
    const int u    = blockIdx.y;
    const int row0 = blockIdx.x * 32;
    const int b    = row0 >> 10;
    const int tid  = threadIdx.x;
    const int px0 = u*2, px1 = u*2+1;
    const int py0 = (u==0)?2:((u==1)?0:1);
    const int py1 = (u==0)?4:((u==1)?5:3);

    projl[0][tid] = ws[OFF_PROJS + ((size_t)u  *BB + b)*DD + tid];
    projl[1][tid] = ws[OFF_PROJX + ((size_t)px0*BB + b)*DD + tid];
    projl[2][tid] = ws[OFF_PROJX + ((size_t)px1*BB + b)*DD + tid];
    projl[3][tid] = ws[OFF_PROJY + ((size_t)py0*BB + b)*DD + tid];
    projl[4][tid] = ws[OFF_PROJY + ((size_t)py1*BB + b)*DD + tid];
    if (tid == 0) {
        csl[0] = ws[OFF_CSS + u*BB + b];
        csl[1] = ws[OFF_CSX + px0*BB + b];
        csl[2] = ws[OFF_CSX + px1*BB + b];
        csl[3] = ws[OFF_CSY + py0*BB + b];
        csl[4] = ws[OFF_CSY + py1*BB + b];
    }
    __syncthreads();
    const float* src = selU(u,u0,u1,u2);
    const int token = tid >> 3, q = tid & 7;
    const int row = row0 + token;
    float a0=0.f,a1=0.f,a2=0.f,a3=0.f,a4=0.f;
    #pragma unroll
    for (int cc = 0; cc < 8; ++cc) {
        const int d0 = q*32 + cc*4;
        const float4 v  = *reinterpret_cast<const float4*>(src + (size_t)row*DD + d0);
        const float4 p0 = *reinterpret_cast<const float4*>(&projl[0][d0]);
        const float4 p1 = *reinterpret_cast<const float4*>(&projl[1][d0]);
        const float4 p2 = *reinterpret_cast<const float4*>(&projl[2][d0]);
        const float4 p3 = *reinterpret_cast<const float4*>(&projl[3][d0]);
        const float4 p4 = *reinterpret_cast<const float4*>(&projl[4][d0]);
        a0 = fmaf(v.x,p0.x,fmaf(v.y,p0.y,fmaf(v.z,p0.z,fmaf(v.w,p0.w,a0))));
        a1 = fmaf(v.x,p1.x,fmaf(v.y,p1.y,fmaf(v.z,p1.z,fmaf(v.w,p1.w,a1))));
        a2 = fmaf(v.x,p2.x,fmaf(v.y,p2.y,fmaf(v.z,p2.z,fmaf(v.w,p2.w,a2))));
        a3 = fmaf(v.x,p3.x,fmaf(v.y,p3.y,fmaf(v.z,p3.z,fmaf(v.w,p3.w,a3))));
        a4 = fmaf(v.x,p4.x,fmaf(v.y,p4.y,fmaf(v.z,p4.z,fmaf(v.w,p4.w,a4))));
    }
    #pragma unroll
    for (int mask = 1; mask <= 4; mask <<= 1) {
        a0 += __shfl_xor(a0, mask, 8);
        a1 += __shfl_xor(a1, mask, 8);
        a2 += __shfl_xor(a2, mask, 8);
        a3 += __shfl_xor(a3, mask, 8);
        a4 += __shfl_xor(a4, mask, 8);
    }
    if (q == 0) {
        ws[OFF_SELFP + (size_t)u  *MM + row] = (a0 + csl[0]) * ws[OFF_INVXS + (size_t)u  *MM + row];
        ws[OFF_POTX  + (size_t)px0*MM + row] = (a1 + csl[1]) * ws[OFF_INVXP + (size_t)px0*MM + row];
        ws[OFF_POTX  + (size_t)px1*MM + row] = (a2 + csl[2]) * ws[OFF_INVXP + (size_t)px1*MM + row];
        ws[OFF_POTY  + (size_t)py0*MM + row] = (a3 + csl[3]) * ws[OFF_INVYP + (size_t)py0*MM + row];
        ws[OFF_POTY  + (size_t)py1*MM + row] = (a4 + csl[4]) * ws[OFF_INVYP + (size_t)py1*MM + row];
    }
}

// ---------------------------------------------------------------------------
// Pass 3a: per (j,b): logits for i=0..2 -> softmax -> normalized probs to ws
// ---------------------------------------------------------------------------
__global__ __launch_bounds__(256) void attend_logits_kernel(
    const float* __restrict__ wdiag, const float* __restrict__ wpair,
    float* __restrict__ ws)
{
    __shared__ float el[3][NN];
    __shared__ float redl[256];
    const int c = blockIdx.x;          // 0..47
    const int j = c >> 4, b = c & 15;
    const int tid = threadIdx.x;

    #pragma unroll
    for (int i = 0; i < 3; ++i) {
        if (i == j) {
            const int p1 = i*2, p2 = i*2+1;
            const float w0 = wdiag[i*4+0], w1 = wdiag[i*4+1], w2 = wdiag[i*4+2], w3 = wdiag[i*4+3];
            for (int n = tid; n < NN; n += 256) {
                const int row = b*NN + n;
                el[i][n] = w0*ws[OFF_UNARY + i*MM + row] + w1*ws[OFF_SELFP + i*MM + row]
                         + w2*ws[OFF_POTX + p1*MM + row] + w3*ws[OFF_POTX + p2*MM + row];
            }
        } else {
            const int p = i*2 + (j > i ? j-1 : j);
            const float w0 = wpair[(i*3+j)*3+0], w1 = wpair[(i*3+j)*3+1], w2 = wpair[(i*3+j)*3+2];
            for (int n = tid; n < NN; n += 256) {
                const int row = b*NN + n;
                el[i][n] = w0*ws[OFF_UNARY + j*MM + row] + w1*ws[OFF_SELFP + j*MM + row]
                         + w2*ws[OFF_POTY + p*MM + row];
            }
        }
    }
    __syncthreads();
    #pragma unroll
    for (int i = 0; i < 3; ++i) {
        float m = -1e30f;
        for (int n = tid; n < NN; n += 256) m = fmaxf(m, el[i][n]);
        redl[tid] = m; __syncthreads();
        for (int st = 128; st > 0; st >>= 1) {
            if (tid < st) redl[tid] = fmaxf(redl[tid], redl[tid+st]);
            __syncthreads();
        }
        m = redl[0];
        __syncthreads();
        float ss = 0.f;
        for (int n = tid; n < NN; n += 256) {
            const float e = expf(el[i][n] - m);
            el[i][n] = e;
            ss += e;
        }
        redl[tid] = ss; __syncthreads();
        for (int st = 128; st > 0; st >>= 1) {
            if (tid < st) redl[tid] += redl[tid+st];
            __syncthreads();
        }
        const float invS = 1.f / redl[0];
        __syncthreads();
        for (int n = tid; n < NN; n += 256)
            ws[OFF_PROB + ((size_t)(i*3+j)*BB + b)*NN + n] = el[i][n] * invS;
    }
}

// ---------------------------------------------------------------------------
// Pass 3b: chunked weighted sum: partial[(i,j,b)][chunk][d]
// ---------------------------------------------------------------------------
__global__ __launch_bounds__(256) void attend_sum_kernel(
    const float* __restrict__ u0, const float* __restrict__ u1, const float* __restrict__ u2,
    const float* __restrict__ ws, float* __restrict__ wso)
{
    __shared__ float pl[3][128];
    const int x  = blockIdx.x;         // 0..383
    const int jb = x >> 3, ch = x & 7;
    const int j = jb >> 4, b = jb & 15;
    const int tid = threadIdx.x;

    for (int t = tid; t < 384; t += 256) {
        const int i = t >> 7, n = t & 127;
        pl[i][n] = ws[OFF_PROB + ((size_t)(i*3+j)*BB + b)*NN + ch*128 + n];
    }
    __syncthreads();
    const float* Uj = selU(j, u0, u1, u2) + ((size_t)b*NN + ch*128)*DD;
    float a0 = 0.f, a1 = 0.f, a2 = 0.f;
    #pragma unroll 4
    for (int n = 0; n < 128; ++n) {
        const float v = Uj[(size_t)n*DD + tid];
        a0 = fmaf(pl[0][n], v, a0);
        a1 = fmaf(pl[1][n], v, a1);
        a2 = fmaf(pl[2][n], v, a2);
    }
    wso[OFF_PART + (((size_t)(0*3+j)*BB + b)*8 + ch)*DD + tid] = a0;
    wso[OFF_PART + (((size_t)(1*3+j)*BB + b)*8 + ch)*DD + tid] = a1;
    wso[OFF_PART + (((size_t)(2*3+j)*BB + b)*8 + ch)*DD + tid] = a2;
}

// ---------------------------------------------------------------------------
// Pass 3c: reduce chunks -> out
// ---------------------------------------------------------------------------
__global__ __launch_bounds__(256) void attend_reduce_kernel(
    const float* __restrict__ ws, float* __restrict__ out)
{
    const int ijb = blockIdx.x;        // 0..143
    const int tid = threadIdx.x;
    float s = 0.f;
    #pragma unroll
    for (int ch = 0; ch < 8; ++ch)
        s += ws[OFF_PART + ((size_t)ijb*8 + ch)*DD + tid];
    out[(size_t)ijb*DD + tid] = s;
}

// ---------------------------------------------------------------------------
extern "C" void kernel_launch(void* const* d_in, const int* in_sizes, int n_in,
                              void* d_out, int out_size, void* d_ws, size_t ws_size,
                              hipStream_t stream)
{
    (void)in_sizes; (void)n_in; (void)out_size; (void)ws_size;
    const float* u0    = (const float*)d_in[0];
    const float* u1    = (const float*)d_in[1];
    const float* u2    = (const float*)d_in[2];
    const float* Wu    = (const float*)d_in[3];
    const float* bu    = (const float*)d_in[4];
    const float* wr    = (const float*)d_in[5];
    const float* br    = (const float*)d_in[6];
    const float* Wsx   = (const float*)d_in[7];
    const float* bsx   = (const float*)d_in[8];
    const float* Wsy   = (const float*)d_in[9];
    const float* bsy   = (const float*)d_in[10];
    const float* Wpx   = (const float*)d_in[11];
    const float* bpx   = (const float*)d_in[12];
    const float* Wpy   = (const float*)d_in[13];
    const float* bpy   = (const float*)d_in[14];
    const float* wdiag = (const float*)d_in[15];
    const float* wpair = (const float*)d_in[16];
    float* ws  = (float*)d_ws;
    float* out = (float*)d_out;

    // zero the atomic accumulators (Ybar, Xpbar, Ypbar are contiguous)
    hipMemsetAsync(ws + OFF_YBAR, 0, (size_t)(NU + 2*NPAIR)*BB*DD*sizeof(float), stream);

    dim3 gw(21, 8);
    convw_kernel<<<gw, 256, 0, stream>>>(Wu, Wsx, Wsy, Wpx, Wpy, ws);

    dim3 g1(MM/128, 3);
    pass1_kernel<<<g1, 256, 0, stream>>>(u0,u1,u2,bu,wr,br,bsx,bsy,bpx,bpy,ws);

    proj_kernel<<<15*BB, 256, 0, stream>>>(Wsx,bsx,Wpx,bpx,Wpy,bpy,ws);
    dim3 g2(MM/32, 3);
    pots_kernel<<<g2, 256, 0, stream>>>(u0,u1,u2,ws);

    attend_logits_kernel<<<3*BB, 256, 0, stream>>>(wdiag, wpair, ws);
    attend_sum_kernel<<<3*BB*8, 256, 0, stream>>>(u0,u1,u2, ws, ws);
    attend_reduce_kernel<<<9*BB, 256, 0, stream>>>(ws, out);
}